// Round 11
// baseline (317.541 us; speedup 1.0000x reference)
//
#include <hip/hip_runtime.h>
#include <cstdint>
#include <cstddef>

using f32x4 = __attribute__((ext_vector_type(4))) float;

#define TDIM 2048
#define HDIM 2048
#define IDIM 1408
#define NEXP 8
#define NKB1 16   // H/128
#define NKB2 11   // I/128
#define MAXM 4096 // T*TOPK

// ---- async global->LDS, 16B/lane. LDS dest: wave-uniform base + lane*16.
__device__ __forceinline__ void gll16(const void* g, void* l) {
  __builtin_amdgcn_global_load_lds(
      (__attribute__((address_space(1))) void*)(uintptr_t)g,
      (__attribute__((address_space(3))) void*)(uint32_t)(uintptr_t)l,
      16, 0, 0);
}

__device__ __forceinline__ f32x4 mfma_fp8(long a, long b, f32x4 c) {
  return __builtin_amdgcn_mfma_f32_16x16x32_fp8_fp8(a, b, c, 0, 0, 0);
}

// fp8 convert (RNE, pre-clamped like reference's clip).
__device__ __forceinline__ uint32_t f8_1(float q) {
  q = fminf(fmaxf(q, -448.f), 448.f);
  return (uint32_t)__builtin_amdgcn_cvt_pk_fp8_f32(q, q, 0, false) & 0xffu;
}

__device__ __forceinline__ float bf16_to_f32(uint32_t bits16) {
  union { uint32_t u; float f; } c;
  c.u = bits16 << 16;
  return c.f;
}

// ============ kernel -1: sniff weight storage dtype + zero cnt ============
__global__ void sniff_kernel(const uint16_t* __restrict__ a,
                             const uint16_t* __restrict__ b,
                             int* __restrict__ modes, int* __restrict__ cnt) {
  if (threadIdx.x < 8) cnt[threadIdx.x] = 0;
  if (threadIdx.x == 0) {
    unsigned acc = 0;
    for (int i = 0; i < 128; ++i) acc |= a[2 * i];
    modes[0] = (acc == 0) ? 1 : 0;   // 1 = f32 storage, 0 = bf16 storage
    acc = 0;
    for (int i = 0; i < 128; ++i) acc |= b[2 * i];
    modes[1] = (acc == 0) ? 1 : 0;
  }
}

// ============ kernel 0: repack weight values -> fp8 bytes (dual dtype) ============
__global__ void repack_kernel(const void* __restrict__ in, uint8_t* __restrict__ out,
                              int n8, const int* __restrict__ modes, int midx) {
  const int i = blockIdx.x * 256 + threadIdx.x;
  if (i >= n8) return;
  const int m = modes[midx];
  float f[8];
  if (m == 1) {            // f32 storage
    const float4* p = (const float4*)in;
    float4 a = p[2 * i], b = p[2 * i + 1];
    f[0] = a.x; f[1] = a.y; f[2] = a.z; f[3] = a.w;
    f[4] = b.x; f[5] = b.y; f[6] = b.z; f[7] = b.w;
  } else {                 // bf16 storage
    uint4 v = ((const uint4*)in)[i];
#pragma unroll
    for (int j = 0; j < 4; ++j) {
      uint32_t w = (&v.x)[j];
      f[2 * j]     = bf16_to_f32(w & 0xffffu);
      f[2 * j + 1] = bf16_to_f32(w >> 16);
    }
  }
  uint32_t lo = 0, hi = 0;
#pragma unroll
  for (int j = 0; j < 8; ++j) {
    uint32_t b8 = f8_1(f[j]);
    if (j < 4) lo |= b8 << (8 * j);
    else       hi |= b8 << (8 * (j - 4));
  }
  ((uint2*)out)[i] = make_uint2(lo, hi);
}

// ============ kernel 1: per-(row,128-block) quantize of hidden_states ============
__global__ void quantx_kernel(const float* __restrict__ x,
                              uint8_t* __restrict__ xq, float* __restrict__ xs) {
  const int gid = blockIdx.x * 4 + (threadIdx.x >> 6);
  const int lane = threadIdx.x & 63;
  const int r = gid >> 4, kb = gid & 15;
  const float2 v = *(const float2*)(x + (size_t)r * HDIM + kb * 128 + lane * 2);
  float a = fmaxf(fabsf(v.x), fabsf(v.y));
#pragma unroll
  for (int d = 1; d < 64; d <<= 1) a = fmaxf(a, __shfl_xor(a, d));
  const float s = fmaxf(a, 1e-12f) / 448.f;
  const uint32_t b0 = f8_1(v.x / s);
  const uint32_t b1 = f8_1(v.y / s);
  *(uint16_t*)(xq + (size_t)r * HDIM + kb * 128 + lane * 2) = (uint16_t)(b0 | (b1 << 8));
  if (lane == 0) xs[r * 16 + kb] = s;
}

// ============ kernel 2: routing -> per-expert slot lists (slot = t*2+k) ============
__global__ void route_kernel(const void* __restrict__ idxraw,
                             int* __restrict__ list, int* __restrict__ cnt) {
  const long long* p = (const long long*)idxraw;
  unsigned hi = 0;
#pragma unroll
  for (int j = 0; j < 16; ++j) hi |= (unsigned)((unsigned long long)p[j] >> 32);
  const int i = blockIdx.x * 256 + threadIdx.x;
  int e;
  if (hi == 0) {
    e = (int)p[i];                       // int64 storage
  } else {
    long long v = p[i >> 1];             // int32 storage
    e = (int)((i & 1) ? (v >> 32) : (v & 0xffffffffLL));
  }
  e &= 7;
  const int pos = atomicAdd(&cnt[e], 1);
  list[e * MAXM + pos] = i;
}

// ============ kernel 3: gate_up GEMM + silu*up + h-quant ============
// 64x(128g+128u) tile, 512 thr (8 waves, 2M x 4N; wave-tile 32x32g+32u), BK=128,
// single-buffer staging. Grid (11, 64, 8) nb fastest. LDS ~43KB -> 3 blocks/CU,
// ~20-24 waves/CU (TLP is the lever; R10 showed 12 waves/CU was the limiter).
__global__ __launch_bounds__(512) void gemm1_kernel(
    const uint8_t* __restrict__ xq, const float* __restrict__ xs,
    const uint8_t* __restrict__ w, const float* __restrict__ wscl,
    const int* __restrict__ list, const int* __restrict__ cnt,
    uint8_t* __restrict__ hq, float* __restrict__ hs) {
  const int e = blockIdx.z, mt = blockIdx.y, nb = blockIdx.x;
  const int M = cnt[e];
  if (mt * 64 >= M) return;
  __shared__ __align__(16) uint8_t As[8192];
  __shared__ __align__(16) uint8_t Bg[16384];
  __shared__ __align__(16) uint8_t Bu[16384];
  __shared__ int slots[64];
  __shared__ __align__(16) float sxs[64];
  __shared__ __align__(16) float amx[256];
  const int tid = threadIdx.x, lane = tid & 63, wid = tid >> 6;
  const int wr = wid >> 2, wc = wid & 3;
  if (tid < 64) {
    int m = mt * 64 + tid;
    slots[tid] = list[e * MAXM + (m < M ? m : 0)];
  }
  __syncthreads();
  const int sr = tid >> 3;                          // staging row 0..63
  const int cj0 = ((tid & 7) ^ (sr & 7)) << 4;      // pre-swizzled source chunk
  const long tokA = slots[sr] >> 1;
  const int my_tok = (tid < 64) ? (slots[tid] >> 1) : 0;
  const uint8_t* pA = xq + tokA * HDIM + cj0;
  const size_t wb = (size_t)e * (2 * IDIM) * HDIM;
  const uint8_t* pG = w + wb + (size_t)(nb * 128 + sr) * HDIM + cj0;
  const uint8_t* pU = w + wb + (size_t)(IDIM + nb * 128 + sr) * HDIM + cj0;
  const float* wsg = wscl + (size_t)e * 352 + nb * 16;   // (E,22,16)
  const float* wsu = wsg + 176;
  const float* pSX = xs + (size_t)my_tok * 16;
  f32x4 accg[2][2] = {};
  f32x4 accu[2][2] = {};
  const int kbyte = (lane >> 4) << 3;
  float rs = (tid < 64) ? pSX[0] : 0.f;   // scale prefetch (kb=0)
  for (int kb = 0; kb < NKB1; ++kb) {
    __syncthreads();   // previous iteration's LDS reads complete
    const int ko = kb << 7;
    gll16(pA + ko, As + tid * 16);
    gll16(pG + ko, Bg + tid * 16);
    gll16(pG + (size_t)64 * HDIM + ko, Bg + 8192 + tid * 16);
    gll16(pU + ko, Bu + tid * 16);
    gll16(pU + (size_t)64 * HDIM + ko, Bu + 8192 + tid * 16);
    if (tid < 64) sxs[tid] = rs;
    __syncthreads();   // drains vmcnt+lgkmcnt: tile ready
    if (kb + 1 < NKB1) rs = (tid < 64) ? pSX[kb + 1] : 0.f;
    const float swg = wsg[kb];
    const float swu = wsu[kb];
    long af[2][4], bgf[2][4], buf_[2][4];
#pragma unroll
    for (int mi = 0; mi < 2; ++mi) {
      const int r = wr * 32 + mi * 16 + (lane & 15);
      const int xr = (r & 7) << 4;
      const uint8_t* bp = As + r * 128;
#pragma unroll
      for (int kc = 0; kc < 4; ++kc)
        af[mi][kc] = *(const long*)(bp + (((kc << 5) + kbyte) ^ xr));
    }
#pragma unroll
    for (int ni = 0; ni < 2; ++ni) {
      const int r = wc * 32 + ni * 16 + (lane & 15);
      const int xr = (r & 7) << 4;
      const uint8_t* bpg = Bg + r * 128;
      const uint8_t* bpu = Bu + r * 128;
#pragma unroll
      for (int kc = 0; kc < 4; ++kc) {
        bgf[ni][kc] = *(const long*)(bpg + (((kc << 5) + kbyte) ^ xr));
        buf_[ni][kc] = *(const long*)(bpu + (((kc << 5) + kbyte) ^ xr));
      }
    }
    f32x4 sxg[2], sxu[2];
#pragma unroll
    for (int mi = 0; mi < 2; ++mi) {
      f32x4 sx = *(const f32x4*)(sxs + wr * 32 + mi * 16 + ((lane >> 4) << 2));
      sxg[mi] = sx * swg;
      sxu[mi] = sx * swu;
    }
#pragma unroll
    for (int mi = 0; mi < 2; ++mi)
#pragma unroll
      for (int ni = 0; ni < 2; ++ni) {
        f32x4 pg = {0.f, 0.f, 0.f, 0.f};
        f32x4 pu = {0.f, 0.f, 0.f, 0.f};
#pragma unroll
        for (int kc = 0; kc < 4; ++kc) {
          pg = mfma_fp8(af[mi][kc], bgf[ni][kc], pg);
          pu = mfma_fp8(af[mi][kc], buf_[ni][kc], pu);
        }
#pragma unroll
        for (int j = 0; j < 4; ++j) {
          accg[mi][ni][j] += pg[j] * sxg[mi][j];
          accu[mi][ni][j] += pu[j] * sxu[mi][j];
        }
      }
  }
  // h = silu(g)*u; rowwise amax over 128 h-cols (one quant block)
  f32x4 hv[2][2];
  f32x4 rmax[2];
#pragma unroll
  for (int mi = 0; mi < 2; ++mi) {
#pragma unroll
    for (int ni = 0; ni < 2; ++ni)
#pragma unroll
      for (int j = 0; j < 4; ++j) {
        float g = accg[mi][ni][j];
        float u = accu[mi][ni][j];
        float h = (g / (1.f + expf(-g))) * u;
        hv[mi][ni][j] = h;
        float ah = fabsf(h);
        rmax[mi][j] = (ni == 0) ? ah : fmaxf(rmax[mi][j], ah);
      }
#pragma unroll
    for (int d = 1; d < 16; d <<= 1)
#pragma unroll
      for (int j = 0; j < 4; ++j)
        rmax[mi][j] = fmaxf(rmax[mi][j], __shfl_xor(rmax[mi][j], d));
  }
  __syncthreads();
  if ((lane & 15) == 0) {
#pragma unroll
    for (int mi = 0; mi < 2; ++mi)
#pragma unroll
      for (int j = 0; j < 4; ++j) {
        int row = wr * 32 + mi * 16 + ((lane >> 4) << 2) + j;
        amx[row * 4 + wc] = rmax[mi][j];
      }
  }
  __syncthreads();
  const int Mrem = M - mt * 64;
#pragma unroll
  for (int mi = 0; mi < 2; ++mi)
#pragma unroll
    for (int j = 0; j < 4; ++j) {
      const int row = wr * 32 + mi * 16 + ((lane >> 4) << 2) + j;
      f32x4 a4 = *(const f32x4*)(amx + row * 4);
      float am = fmaxf(fmaxf(a4[0], a4[1]), fmaxf(a4[2], a4[3]));
      float sq = fmaxf(am, 1e-12f) / 448.f;
      if (row < Mrem) {
        const int slot = slots[row];
        uint8_t* hp = hq + (size_t)slot * IDIM + nb * 128 + wc * 32 + (lane & 15);
        hp[0]  = (uint8_t)f8_1(hv[mi][0][j] / sq);
        hp[16] = (uint8_t)f8_1(hv[mi][1][j] / sq);
        if (wc == 0 && (lane & 15) == 0) hs[slot * 16 + nb] = sq;  // stride 16
      }
    }
}

// ============ kernel 4: down GEMM -> per-slot tmp (plain stores) ============
// 64x128 tile, 512 thr (8 waves, 2M x 4N; wave-tile 32x32), BK=128,
// single-buffer. Grid (16, 64, 8): ~1024 working blocks.
__global__ __launch_bounds__(512) void gemm2_kernel(
    const uint8_t* __restrict__ hq, const float* __restrict__ hs,
    const uint8_t* __restrict__ w, const float* __restrict__ wscl,
    const int* __restrict__ list, const int* __restrict__ cnt,
    const float* __restrict__ tkw, float* __restrict__ tmp) {
  const int e = blockIdx.z, mt = blockIdx.y, nt = blockIdx.x;
  const int M = cnt[e];
  if (mt * 64 >= M) return;
  __shared__ __align__(16) uint8_t As[8192];
  __shared__ __align__(16) uint8_t Bs[16384];
  __shared__ int slots[64];
  __shared__ float rwl[64];
  __shared__ __align__(16) float sxs[64];
  const int tid = threadIdx.x, lane = tid & 63, wid = tid >> 6;
  const int wr = wid >> 2, wc = wid & 3;
  if (tid < 64) {
    int m = mt * 64 + tid;
    int slot = list[e * MAXM + (m < M ? m : 0)];
    slots[tid] = slot;
    rwl[tid] = (m < M) ? tkw[slot] : 0.f;
  }
  __syncthreads();
  const int sr = tid >> 3;
  const int cj0 = ((tid & 7) ^ (sr & 7)) << 4;
  const long sA = slots[sr];
  const int my_slot = (tid < 64) ? slots[tid] : 0;
  const uint8_t* pA = hq + sA * IDIM + cj0;
  const uint8_t* pB = w + (size_t)e * HDIM * IDIM + (size_t)(nt * 128 + sr) * IDIM + cj0;
  const float* wsd = wscl + (size_t)e * 176 + nt * 11;  // (E,16,11)
  const float* pSX = hs + (size_t)my_slot * 16;
  f32x4 acc[2][2] = {};
  const int kbyte = (lane >> 4) << 3;
  float rs = (tid < 64) ? pSX[0] : 0.f;
  for (int kb = 0; kb < NKB2; ++kb) {
    __syncthreads();
    const int ko = kb << 7;
    gll16(pA + ko, As + tid * 16);
    gll16(pB + ko, Bs + tid * 16);
    gll16(pB + (size_t)64 * IDIM + ko, Bs + 8192 + tid * 16);
    if (tid < 64) sxs[tid] = rs;
    __syncthreads();
    if (kb + 1 < NKB2) rs = (tid < 64) ? pSX[kb + 1] : 0.f;
    const float swd = wsd[kb];
    long af[2][4], bf[2][4];
#pragma unroll
    for (int mi = 0; mi < 2; ++mi) {
      const int r = wr * 32 + mi * 16 + (lane & 15);
      const int xr = (r & 7) << 4;
      const uint8_t* bp = As + r * 128;
#pragma unroll
      for (int kc = 0; kc < 4; ++kc)
        af[mi][kc] = *(const long*)(bp + (((kc << 5) + kbyte) ^ xr));
    }
#pragma unroll
    for (int ni = 0; ni < 2; ++ni) {
      const int r = wc * 32 + ni * 16 + (lane & 15);
      const int xr = (r & 7) << 4;
      const uint8_t* bp = Bs + r * 128;
#pragma unroll
      for (int kc = 0; kc < 4; ++kc)
        bf[ni][kc] = *(const long*)(bp + (((kc << 5) + kbyte) ^ xr));
    }
    f32x4 sxd[2];
#pragma unroll
    for (int mi = 0; mi < 2; ++mi) {
      f32x4 sx = *(const f32x4*)(sxs + wr * 32 + mi * 16 + ((lane >> 4) << 2));
      sxd[mi] = sx * swd;
    }
#pragma unroll
    for (int mi = 0; mi < 2; ++mi)
#pragma unroll
      for (int ni = 0; ni < 2; ++ni) {
        f32x4 p = {0.f, 0.f, 0.f, 0.f};
#pragma unroll
        for (int kc = 0; kc < 4; ++kc) p = mfma_fp8(af[mi][kc], bf[ni][kc], p);
#pragma unroll
        for (int j = 0; j < 4; ++j) acc[mi][ni][j] += p[j] * sxd[mi][j];
      }
  }
  const int Mrem = M - mt * 64;
#pragma unroll
  for (int mi = 0; mi < 2; ++mi)
#pragma unroll
    for (int j = 0; j < 4; ++j) {
      const int row = wr * 32 + mi * 16 + ((lane >> 4) << 2) + j;
      if (row < Mrem) {
        const int slot = slots[row];
        const float rw = rwl[row];
        float* op = tmp + (size_t)slot * HDIM + nt * 128 + wc * 32 + (lane & 15);
        op[0]  = rw * acc[mi][0][j];
        op[16] = rw * acc[mi][1][j];
      }
    }
}

// ============ kernel 5: out[t] = tmp[2t] + tmp[2t+1] ============
__global__ void reduce_kernel(const float* __restrict__ tmp, float* __restrict__ out) {
  const int i = blockIdx.x * 256 + threadIdx.x;
  const int t = i >> 9, c4 = i & 511;
  const f32x4 a = ((const f32x4*)tmp)[(size_t)(2 * t) * 512 + c4];
  const f32x4 c = ((const f32x4*)tmp)[(size_t)(2 * t) * 512 + 512 + c4];
  ((f32x4*)out)[i] = a + c;
}

extern "C" void kernel_launch(void* const* d_in, const int* in_sizes, int n_in,
                              void* d_out, int out_size, void* d_ws, size_t ws_size,
                              hipStream_t stream) {
  const float* hidden = (const float*)d_in[0];
  const void* topk_idx = d_in[1];
  const float* topk_w = (const float*)d_in[2];
  const void* gup_raw = d_in[3];   // fp8 values held as f32 or bf16 (sniffed)
  const float* gup_s = (const float*)d_in[4];
  const void* dwn_raw = d_in[5];
  const float* dwn_s = (const float*)d_in[6];
  float* out = (float*)d_out;
  uint8_t* ws = (uint8_t*)d_ws;
  // workspace layout (~79.7 MB); tmp (32MB) aliases gq (dead after gemm1)
  uint8_t* xq = ws;                           //  4,194,304
  float* xs = (float*)(ws + 4194304);         //    131,072
  uint8_t* hq = ws + 4325376;                 //  5,767,168
  float* hs = (float*)(ws + 10092544);        //    262,144 (4096 x 16 f32, padded)
  int* list = (int*)(ws + 10354688);          //    131,072
  int* cnt = (int*)(ws + 10485760);           //         64
  int* modes = (int*)(ws + 10485824);         //         64
  uint8_t* gq = ws + 10485888;                // 46,137,344 (gate_up fp8)
  float* tmp = (float*)gq;                    // 33,554,432 (aliases gq; gemm2/reduce only)
  uint8_t* dq = ws + 56623232;                // 23,068,672 (down fp8)
  (void)in_sizes; (void)n_in; (void)ws_size; (void)out_size;

  sniff_kernel<<<1, 64, 0, stream>>>((const uint16_t*)gup_raw, (const uint16_t*)dwn_raw, modes, cnt);
  repack_kernel<<<(5767168 + 255) / 256, 256, 0, stream>>>(gup_raw, gq, 5767168, modes, 0);
  repack_kernel<<<(2883584 + 255) / 256, 256, 0, stream>>>(dwn_raw, dq, 2883584, modes, 1);
  quantx_kernel<<<8192, 256, 0, stream>>>(hidden, xq, xs);
  route_kernel<<<16, 256, 0, stream>>>(topk_idx, list, cnt);
  gemm1_kernel<<<dim3(11, 64, 8), 512, 0, stream>>>(xq, xs, gq, gup_s, list, cnt, hq, hs);
  gemm2_kernel<<<dim3(16, 64, 8), 512, 0, stream>>>(hq, hs, dq, dwn_s, list, cnt, topk_w, tmp);
  reduce_kernel<<<4096, 256, 0, stream>>>(tmp, out);
}

// Round 12
// 262.567 us; speedup vs baseline: 1.2094x; 1.2094x over previous
//
#include <hip/hip_runtime.h>
#include <cstdint>
#include <cstddef>

using f32x4 = __attribute__((ext_vector_type(4))) float;

#define TDIM 2048
#define HDIM 2048
#define IDIM 1408
#define NEXP 8
#define NKB1 16   // H/128
#define NKB2 11   // I/128
#define MAXM 4096 // T*TOPK

// ---- async global->LDS, 16B/lane. LDS dest: wave-uniform base + lane*16.
__device__ __forceinline__ void gll16(const void* g, void* l) {
  __builtin_amdgcn_global_load_lds(
      (__attribute__((address_space(1))) void*)(uintptr_t)g,
      (__attribute__((address_space(3))) void*)(uint32_t)(uintptr_t)l,
      16, 0, 0);
}

__device__ __forceinline__ f32x4 mfma_fp8(long a, long b, f32x4 c) {
  return __builtin_amdgcn_mfma_f32_16x16x32_fp8_fp8(a, b, c, 0, 0, 0);
}

// fp8 convert (RNE, pre-clamped like reference's clip).
__device__ __forceinline__ uint32_t f8_1(float q) {
  q = fminf(fmaxf(q, -448.f), 448.f);
  return (uint32_t)__builtin_amdgcn_cvt_pk_fp8_f32(q, q, 0, false) & 0xffu;
}

__device__ __forceinline__ float bf16_to_f32(uint32_t bits16) {
  union { uint32_t u; float f; } c;
  c.u = bits16 << 16;
  return c.f;
}

// ============ kernel -1: sniff weight storage dtype + zero cnt ============
__global__ void sniff_kernel(const uint16_t* __restrict__ a,
                             const uint16_t* __restrict__ b,
                             int* __restrict__ modes, int* __restrict__ cnt) {
  if (threadIdx.x < 8) cnt[threadIdx.x] = 0;
  if (threadIdx.x == 0) {
    unsigned acc = 0;
    for (int i = 0; i < 128; ++i) acc |= a[2 * i];
    modes[0] = (acc == 0) ? 1 : 0;   // 1 = f32 storage, 0 = bf16 storage
    acc = 0;
    for (int i = 0; i < 128; ++i) acc |= b[2 * i];
    modes[1] = (acc == 0) ? 1 : 0;
  }
}

// ============ kernel 0: repack weight values -> fp8 bytes (dual dtype) ============
__global__ void repack_kernel(const void* __restrict__ in, uint8_t* __restrict__ out,
                              int n8, const int* __restrict__ modes, int midx) {
  const int i = blockIdx.x * 256 + threadIdx.x;
  if (i >= n8) return;
  const int m = modes[midx];
  float f[8];
  if (m == 1) {            // f32 storage
    const float4* p = (const float4*)in;
    float4 a = p[2 * i], b = p[2 * i + 1];
    f[0] = a.x; f[1] = a.y; f[2] = a.z; f[3] = a.w;
    f[4] = b.x; f[5] = b.y; f[6] = b.z; f[7] = b.w;
  } else {                 // bf16 storage
    uint4 v = ((const uint4*)in)[i];
#pragma unroll
    for (int j = 0; j < 4; ++j) {
      uint32_t w = (&v.x)[j];
      f[2 * j]     = bf16_to_f32(w & 0xffffu);
      f[2 * j + 1] = bf16_to_f32(w >> 16);
    }
  }
  uint32_t lo = 0, hi = 0;
#pragma unroll
  for (int j = 0; j < 8; ++j) {
    uint32_t b8 = f8_1(f[j]);
    if (j < 4) lo |= b8 << (8 * j);
    else       hi |= b8 << (8 * (j - 4));
  }
  ((uint2*)out)[i] = make_uint2(lo, hi);
}

// ============ kernel 1: per-(row,128-block) quantize of hidden_states ============
__global__ void quantx_kernel(const float* __restrict__ x,
                              uint8_t* __restrict__ xq, float* __restrict__ xs) {
  const int gid = blockIdx.x * 4 + (threadIdx.x >> 6);
  const int lane = threadIdx.x & 63;
  const int r = gid >> 4, kb = gid & 15;
  const float2 v = *(const float2*)(x + (size_t)r * HDIM + kb * 128 + lane * 2);
  float a = fmaxf(fabsf(v.x), fabsf(v.y));
#pragma unroll
  for (int d = 1; d < 64; d <<= 1) a = fmaxf(a, __shfl_xor(a, d));
  const float s = fmaxf(a, 1e-12f) / 448.f;
  const uint32_t b0 = f8_1(v.x / s);
  const uint32_t b1 = f8_1(v.y / s);
  *(uint16_t*)(xq + (size_t)r * HDIM + kb * 128 + lane * 2) = (uint16_t)(b0 | (b1 << 8));
  if (lane == 0) xs[r * 16 + kb] = s;
}

// ============ kernel 2: routing -> per-expert slot lists (slot = t*2+k) ============
__global__ void route_kernel(const void* __restrict__ idxraw,
                             int* __restrict__ list, int* __restrict__ cnt) {
  const long long* p = (const long long*)idxraw;
  unsigned hi = 0;
#pragma unroll
  for (int j = 0; j < 16; ++j) hi |= (unsigned)((unsigned long long)p[j] >> 32);
  const int i = blockIdx.x * 256 + threadIdx.x;
  int e;
  if (hi == 0) {
    e = (int)p[i];                       // int64 storage
  } else {
    long long v = p[i >> 1];             // int32 storage
    e = (int)((i & 1) ? (v >> 32) : (v & 0xffffffffLL));
  }
  e &= 7;
  const int pos = atomicAdd(&cnt[e], 1);
  list[e * MAXM + pos] = i;
}

// ============ kernel 3: gate_up GEMM + silu*up + h-quant ============
// 64x(128g+128u) tile, 256 thr (4 waves, 2M x 2N), BK=128, single-buffer.
// Flat grid 5632 = 8 XCD x (11nb x 64mt), expert e pinned to XCD e (b&7),
// mt FASTEST within XCD -> co-resident blocks share one weight panel in L2.
__global__ __launch_bounds__(256) void gemm1_kernel(
    const uint8_t* __restrict__ xq, const float* __restrict__ xs,
    const uint8_t* __restrict__ w, const float* __restrict__ wscl,
    const int* __restrict__ list, const int* __restrict__ cnt,
    uint8_t* __restrict__ hq, float* __restrict__ hs) {
  const int b = blockIdx.x;
  const int e = b & 7;
  const int idx = b >> 3;          // 0..703
  const int mt = idx & 63;         // fastest: neighbors share the nb panel
  const int nb = idx >> 6;         // 0..10
  const int M = cnt[e];
  if (mt * 64 >= M) return;
  __shared__ __align__(16) uint8_t As[8192];
  __shared__ __align__(16) uint8_t Bg[16384];
  __shared__ __align__(16) uint8_t Bu[16384];
  __shared__ int slots[64];
  __shared__ __align__(16) float sxs[64];
  __shared__ __align__(16) float amx[128];
  const int tid = threadIdx.x, lane = tid & 63, wid = tid >> 6;
  const int wr = wid >> 1, wc = wid & 1;
  if (tid < 64) {
    int m = mt * 64 + tid;
    slots[tid] = list[e * MAXM + (m < M ? m : 0)];
  }
  __syncthreads();
  const int s = tid >> 3;                           // 0..31
  const int cj0 = ((tid & 7) ^ (s & 7)) << 4;       // pre-swizzled source chunk
  const long tokA0 = slots[s] >> 1;
  const long tokA1 = slots[s + 32] >> 1;
  const int my_tok = (tid < 64) ? (slots[tid] >> 1) : 0;
  const uint8_t* pA0 = xq + tokA0 * HDIM + cj0;
  const uint8_t* pA1 = xq + tokA1 * HDIM + cj0;
  const size_t wb = (size_t)e * (2 * IDIM) * HDIM;
  const uint8_t* pG = w + wb + (size_t)(nb * 128 + s) * HDIM + cj0;
  const uint8_t* pU = w + wb + (size_t)(IDIM + nb * 128 + s) * HDIM + cj0;
  const float* wsg = wscl + (size_t)e * 352 + nb * 16;   // (E,22,16)
  const float* wsu = wsg + 176;
  const float* pSX = xs + (size_t)my_tok * 16;
  f32x4 accg[2][4] = {};
  f32x4 accu[2][4] = {};
  const int kbyte = (lane >> 4) << 3;
  float rs = (tid < 64) ? pSX[0] : 0.f;
  for (int kb = 0; kb < NKB1; ++kb) {
    __syncthreads();   // previous iteration's LDS reads complete
    const int ko = kb << 7;
    gll16(pA0 + ko, As + tid * 16);
    gll16(pA1 + ko, As + 4096 + tid * 16);
#pragma unroll
    for (int k = 0; k < 4; ++k) {
      gll16(pG + (size_t)(k * 32) * HDIM + ko, Bg + k * 4096 + tid * 16);
      gll16(pU + (size_t)(k * 32) * HDIM + ko, Bu + k * 4096 + tid * 16);
    }
    if (tid < 64) sxs[tid] = rs;
    __syncthreads();   // drains vmcnt+lgkmcnt: tile ready
    if (kb + 1 < NKB1) rs = (tid < 64) ? pSX[kb + 1] : 0.f;
    const float swg = wsg[kb];
    const float swu = wsu[kb];
    long af[2][4], bgf[4][4], buf_[4][4];
#pragma unroll
    for (int mi = 0; mi < 2; ++mi) {
      const int r = wr * 32 + mi * 16 + (lane & 15);
      const int xr = (r & 7) << 4;
      const uint8_t* bp = As + r * 128;
#pragma unroll
      for (int kc = 0; kc < 4; ++kc)
        af[mi][kc] = *(const long*)(bp + (((kc << 5) + kbyte) ^ xr));
    }
#pragma unroll
    for (int ni = 0; ni < 4; ++ni) {
      const int r = wc * 64 + ni * 16 + (lane & 15);
      const int xr = (r & 7) << 4;
      const uint8_t* bpg = Bg + r * 128;
      const uint8_t* bpu = Bu + r * 128;
#pragma unroll
      for (int kc = 0; kc < 4; ++kc) {
        bgf[ni][kc] = *(const long*)(bpg + (((kc << 5) + kbyte) ^ xr));
        buf_[ni][kc] = *(const long*)(bpu + (((kc << 5) + kbyte) ^ xr));
      }
    }
    f32x4 sxg[2], sxu[2];
#pragma unroll
    for (int mi = 0; mi < 2; ++mi) {
      f32x4 sx = *(const f32x4*)(sxs + wr * 32 + mi * 16 + ((lane >> 4) << 2));
      sxg[mi] = sx * swg;
      sxu[mi] = sx * swu;
    }
#pragma unroll
    for (int mi = 0; mi < 2; ++mi)
#pragma unroll
      for (int ni = 0; ni < 4; ++ni) {
        f32x4 pg = {0.f, 0.f, 0.f, 0.f};
        f32x4 pu = {0.f, 0.f, 0.f, 0.f};
#pragma unroll
        for (int kc = 0; kc < 4; ++kc) {
          pg = mfma_fp8(af[mi][kc], bgf[ni][kc], pg);
          pu = mfma_fp8(af[mi][kc], buf_[ni][kc], pu);
        }
#pragma unroll
        for (int j = 0; j < 4; ++j) {
          accg[mi][ni][j] += pg[j] * sxg[mi][j];
          accu[mi][ni][j] += pu[j] * sxu[mi][j];
        }
      }
  }
  // h = silu(g)*u; rowwise amax over 128 h-cols (one quant block)
  f32x4 hv[2][4];
  f32x4 rmax[2];
#pragma unroll
  for (int mi = 0; mi < 2; ++mi) {
#pragma unroll
    for (int ni = 0; ni < 4; ++ni)
#pragma unroll
      for (int j = 0; j < 4; ++j) {
        float g = accg[mi][ni][j];
        float u = accu[mi][ni][j];
        float h = (g / (1.f + expf(-g))) * u;
        hv[mi][ni][j] = h;
        float ah = fabsf(h);
        rmax[mi][j] = (ni == 0) ? ah : fmaxf(rmax[mi][j], ah);
      }
#pragma unroll
    for (int d = 1; d < 16; d <<= 1)
#pragma unroll
      for (int j = 0; j < 4; ++j)
        rmax[mi][j] = fmaxf(rmax[mi][j], __shfl_xor(rmax[mi][j], d));
  }
  __syncthreads();
  if ((lane & 15) == 0) {
#pragma unroll
    for (int mi = 0; mi < 2; ++mi)
#pragma unroll
      for (int j = 0; j < 4; ++j) {
        int row = wr * 32 + mi * 16 + ((lane >> 4) << 2) + j;
        amx[row * 2 + wc] = rmax[mi][j];
      }
  }
  __syncthreads();
  const int Mrem = M - mt * 64;
#pragma unroll
  for (int mi = 0; mi < 2; ++mi)
#pragma unroll
    for (int j = 0; j < 4; ++j) {
      const int row = wr * 32 + mi * 16 + ((lane >> 4) << 2) + j;
      float am = fmaxf(amx[row * 2], amx[row * 2 + 1]);
      float sq = fmaxf(am, 1e-12f) / 448.f;
      if (row < Mrem) {
        const int slot = slots[row];
        uint8_t* hp = hq + (size_t)slot * IDIM + nb * 128 + wc * 64 + (lane & 15);
#pragma unroll
        for (int ni = 0; ni < 4; ++ni)
          hp[ni * 16] = (uint8_t)f8_1(hv[mi][ni][j] / sq);
        if (wc == 0 && (lane & 15) == 0) hs[slot * 16 + nb] = sq;  // stride 16
      }
    }
}

// ============ kernel 4: down GEMM -> per-slot tmp (plain stores) ============
// 128x128 tile, 256 thr (4 waves, 2M x 2N), BK=128, single-buffer.
// Flat grid 4096 = 8 XCD x (16nt x 32mt), expert->XCD, mt fastest.
__global__ __launch_bounds__(256) void gemm2_kernel(
    const uint8_t* __restrict__ hq, const float* __restrict__ hs,
    const uint8_t* __restrict__ w, const float* __restrict__ wscl,
    const int* __restrict__ list, const int* __restrict__ cnt,
    const float* __restrict__ tkw, float* __restrict__ tmp) {
  const int b = blockIdx.x;
  const int e = b & 7;
  const int idx = b >> 3;          // 0..511
  const int mt = idx & 31;         // fastest
  const int nt = idx >> 5;         // 0..15
  const int M = cnt[e];
  if (mt * 128 >= M) return;
  __shared__ __align__(16) uint8_t As[16384];
  __shared__ __align__(16) uint8_t Bs[16384];
  __shared__ int slots[128];
  __shared__ float rwl[128];
  __shared__ __align__(16) float sxs[128];
  const int tid = threadIdx.x, lane = tid & 63, wid = tid >> 6;
  const int wr = wid >> 1, wc = wid & 1;
  if (tid < 128) {
    int m = mt * 128 + tid;
    int slot = list[e * MAXM + (m < M ? m : 0)];
    slots[tid] = slot;
    rwl[tid] = (m < M) ? tkw[slot] : 0.f;
  }
  __syncthreads();
  const int s = tid >> 3;
  const int cj0 = ((tid & 7) ^ (s & 7)) << 4;
  const long sA0 = slots[s];
  const long sA1 = slots[s + 32];
  const long sA2 = slots[s + 64];
  const long sA3 = slots[s + 96];
  const int my_slot = (tid < 128) ? slots[tid] : 0;
  const uint8_t* pA0 = hq + sA0 * IDIM + cj0;
  const uint8_t* pA1 = hq + sA1 * IDIM + cj0;
  const uint8_t* pA2 = hq + sA2 * IDIM + cj0;
  const uint8_t* pA3 = hq + sA3 * IDIM + cj0;
  const uint8_t* pB = w + (size_t)e * HDIM * IDIM + (size_t)(nt * 128 + s) * IDIM + cj0;
  const float* wsd = wscl + (size_t)e * 176 + nt * 11;  // (E,16,11)
  const float* pSX = hs + (size_t)my_slot * 16;
  f32x4 acc[4][4] = {};
  const int kbyte = (lane >> 4) << 3;
  float rs = (tid < 128) ? pSX[0] : 0.f;
  for (int kb = 0; kb < NKB2; ++kb) {
    __syncthreads();
    const int ko = kb << 7;
    gll16(pA0 + ko, As + tid * 16);
    gll16(pA1 + ko, As + 4096 + tid * 16);
    gll16(pA2 + ko, As + 8192 + tid * 16);
    gll16(pA3 + ko, As + 12288 + tid * 16);
#pragma unroll
    for (int k = 0; k < 4; ++k)
      gll16(pB + (size_t)(k * 32) * IDIM + ko, Bs + k * 4096 + tid * 16);
    if (tid < 128) sxs[tid] = rs;
    __syncthreads();
    if (kb + 1 < NKB2) rs = (tid < 128) ? pSX[kb + 1] : 0.f;
    const float swd = wsd[kb];
    long af[4][4], bf[4][4];
#pragma unroll
    for (int mi = 0; mi < 4; ++mi) {
      const int r = wr * 64 + mi * 16 + (lane & 15);
      const int xr = (r & 7) << 4;
      const uint8_t* bp = As + r * 128;
#pragma unroll
      for (int kc = 0; kc < 4; ++kc)
        af[mi][kc] = *(const long*)(bp + (((kc << 5) + kbyte) ^ xr));
    }
#pragma unroll
    for (int ni = 0; ni < 4; ++ni) {
      const int r = wc * 64 + ni * 16 + (lane & 15);
      const int xr = (r & 7) << 4;
      const uint8_t* bp = Bs + r * 128;
#pragma unroll
      for (int kc = 0; kc < 4; ++kc)
        bf[ni][kc] = *(const long*)(bp + (((kc << 5) + kbyte) ^ xr));
    }
    f32x4 sxd[4];
#pragma unroll
    for (int mi = 0; mi < 4; ++mi) {
      f32x4 sx = *(const f32x4*)(sxs + wr * 64 + mi * 16 + ((lane >> 4) << 2));
      sxd[mi] = sx * swd;
    }
#pragma unroll
    for (int mi = 0; mi < 4; ++mi)
#pragma unroll
      for (int ni = 0; ni < 4; ++ni) {
        f32x4 p = {0.f, 0.f, 0.f, 0.f};
#pragma unroll
        for (int kc = 0; kc < 4; ++kc) p = mfma_fp8(af[mi][kc], bf[ni][kc], p);
#pragma unroll
        for (int j = 0; j < 4; ++j) acc[mi][ni][j] += p[j] * sxd[mi][j];
      }
  }
  const int Mrem = M - mt * 128;
#pragma unroll
  for (int mi = 0; mi < 4; ++mi)
#pragma unroll
    for (int j = 0; j < 4; ++j) {
      const int row = wr * 64 + mi * 16 + ((lane >> 4) << 2) + j;
      if (row < Mrem) {
        const int slot = slots[row];
        const float rw = rwl[row];
        float* op = tmp + (size_t)slot * HDIM + nt * 128 + wc * 64 + (lane & 15);
#pragma unroll
        for (int ni = 0; ni < 4; ++ni) op[ni * 16] = rw * acc[mi][ni][j];
      }
    }
}

// ============ kernel 5: out[t] = tmp[2t] + tmp[2t+1] ============
__global__ void reduce_kernel(const float* __restrict__ tmp, float* __restrict__ out) {
  const int i = blockIdx.x * 256 + threadIdx.x;
  const int t = i >> 9, c4 = i & 511;
  const f32x4 a = ((const f32x4*)tmp)[(size_t)(2 * t) * 512 + c4];
  const f32x4 c = ((const f32x4*)tmp)[(size_t)(2 * t) * 512 + 512 + c4];
  ((f32x4*)out)[i] = a + c;
}

extern "C" void kernel_launch(void* const* d_in, const int* in_sizes, int n_in,
                              void* d_out, int out_size, void* d_ws, size_t ws_size,
                              hipStream_t stream) {
  const float* hidden = (const float*)d_in[0];
  const void* topk_idx = d_in[1];
  const float* topk_w = (const float*)d_in[2];
  const void* gup_raw = d_in[3];   // fp8 values held as f32 or bf16 (sniffed)
  const float* gup_s = (const float*)d_in[4];
  const void* dwn_raw = d_in[5];
  const float* dwn_s = (const float*)d_in[6];
  float* out = (float*)d_out;
  uint8_t* ws = (uint8_t*)d_ws;
  // workspace layout (~79.7 MB); tmp (32MB) aliases gq (dead after gemm1)
  uint8_t* xq = ws;                           //  4,194,304
  float* xs = (float*)(ws + 4194304);         //    131,072
  uint8_t* hq = ws + 4325376;                 //  5,767,168
  float* hs = (float*)(ws + 10092544);        //    262,144 (4096 x 16 f32, padded)
  int* list = (int*)(ws + 10354688);          //    131,072
  int* cnt = (int*)(ws + 10485760);           //         64
  int* modes = (int*)(ws + 10485824);         //         64
  uint8_t* gq = ws + 10485888;                // 46,137,344 (gate_up fp8)
  float* tmp = (float*)gq;                    // 33,554,432 (aliases gq; gemm2/reduce only)
  uint8_t* dq = ws + 56623232;                // 23,068,672 (down fp8)
  (void)in_sizes; (void)n_in; (void)ws_size; (void)out_size;

  sniff_kernel<<<1, 64, 0, stream>>>((const uint16_t*)gup_raw, (const uint16_t*)dwn_raw, modes, cnt);
  repack_kernel<<<(5767168 + 255) / 256, 256, 0, stream>>>(gup_raw, gq, 5767168, modes, 0);
  repack_kernel<<<(2883584 + 255) / 256, 256, 0, stream>>>(dwn_raw, dq, 2883584, modes, 1);
  quantx_kernel<<<8192, 256, 0, stream>>>(hidden, xq, xs);
  route_kernel<<<16, 256, 0, stream>>>(topk_idx, list, cnt);
  gemm1_kernel<<<5632, 256, 0, stream>>>(xq, xs, gq, gup_s, list, cnt, hq, hs);
  gemm2_kernel<<<4096, 256, 0, stream>>>(hq, hs, dq, dwn_s, list, cnt, topk_w, tmp);
  reduce_kernel<<<4096, 256, 0, stream>>>(tmp, out);
}

// Round 13
// 226.886 us; speedup vs baseline: 1.3996x; 1.1573x over previous
//
#include <hip/hip_runtime.h>
#include <cstdint>
#include <cstddef>

using f32x4 = __attribute__((ext_vector_type(4))) float;

#define TDIM 2048
#define HDIM 2048
#define IDIM 1408
#define NEXP 8
#define NKB1 16   // H/128
#define NKB2 11   // I/128
#define MAXM 4096 // T*TOPK

// ---- async global->LDS, 16B/lane. LDS dest: wave-uniform base + lane*16.
__device__ __forceinline__ void gll16(const void* g, void* l) {
  __builtin_amdgcn_global_load_lds(
      (__attribute__((address_space(1))) void*)(uintptr_t)g,
      (__attribute__((address_space(3))) void*)(uint32_t)(uintptr_t)l,
      16, 0, 0);
}

__device__ __forceinline__ f32x4 mfma_fp8(long a, long b, f32x4 c) {
  return __builtin_amdgcn_mfma_f32_16x16x32_fp8_fp8(a, b, c, 0, 0, 0);
}

// fp8 convert (RNE, pre-clamped like reference's clip).
__device__ __forceinline__ uint32_t f8_1(float q) {
  q = fminf(fmaxf(q, -448.f), 448.f);
  return (uint32_t)__builtin_amdgcn_cvt_pk_fp8_f32(q, q, 0, false) & 0xffu;
}

__device__ __forceinline__ float bf16_to_f32(uint32_t bits16) {
  union { uint32_t u; float f; } c;
  c.u = bits16 << 16;
  return c.f;
}

// ============ kernel -1: sniff weight storage dtype + zero cnt ============
__global__ void sniff_kernel(const uint16_t* __restrict__ a,
                             const uint16_t* __restrict__ b,
                             int* __restrict__ modes, int* __restrict__ cnt) {
  if (threadIdx.x < 8) cnt[threadIdx.x] = 0;
  if (threadIdx.x == 0) {
    unsigned acc = 0;
    for (int i = 0; i < 128; ++i) acc |= a[2 * i];
    modes[0] = (acc == 0) ? 1 : 0;   // 1 = f32 storage, 0 = bf16 storage
    acc = 0;
    for (int i = 0; i < 128; ++i) acc |= b[2 * i];
    modes[1] = (acc == 0) ? 1 : 0;
  }
}

// ============ kernel 0: repack weight values -> fp8 bytes (dual dtype) ============
__global__ void repack_kernel(const void* __restrict__ in, uint8_t* __restrict__ out,
                              int n8, const int* __restrict__ modes, int midx) {
  const int i = blockIdx.x * 256 + threadIdx.x;
  if (i >= n8) return;
  const int m = modes[midx];
  float f[8];
  if (m == 1) {            // f32 storage
    const float4* p = (const float4*)in;
    float4 a = p[2 * i], b = p[2 * i + 1];
    f[0] = a.x; f[1] = a.y; f[2] = a.z; f[3] = a.w;
    f[4] = b.x; f[5] = b.y; f[6] = b.z; f[7] = b.w;
  } else {                 // bf16 storage
    uint4 v = ((const uint4*)in)[i];
#pragma unroll
    for (int j = 0; j < 4; ++j) {
      uint32_t w = (&v.x)[j];
      f[2 * j]     = bf16_to_f32(w & 0xffffu);
      f[2 * j + 1] = bf16_to_f32(w >> 16);
    }
  }
  uint32_t lo = 0, hi = 0;
#pragma unroll
  for (int j = 0; j < 8; ++j) {
    uint32_t b8 = f8_1(f[j]);
    if (j < 4) lo |= b8 << (8 * j);
    else       hi |= b8 << (8 * (j - 4));
  }
  ((uint2*)out)[i] = make_uint2(lo, hi);
}

// ============ kernel 1: per-(row,128-block) quantize of hidden_states ============
__global__ void quantx_kernel(const float* __restrict__ x,
                              uint8_t* __restrict__ xq, float* __restrict__ xs) {
  const int gid = blockIdx.x * 4 + (threadIdx.x >> 6);
  const int lane = threadIdx.x & 63;
  const int r = gid >> 4, kb = gid & 15;
  const float2 v = *(const float2*)(x + (size_t)r * HDIM + kb * 128 + lane * 2);
  float a = fmaxf(fabsf(v.x), fabsf(v.y));
#pragma unroll
  for (int d = 1; d < 64; d <<= 1) a = fmaxf(a, __shfl_xor(a, d));
  const float s = fmaxf(a, 1e-12f) / 448.f;
  const uint32_t b0 = f8_1(v.x / s);
  const uint32_t b1 = f8_1(v.y / s);
  *(uint16_t*)(xq + (size_t)r * HDIM + kb * 128 + lane * 2) = (uint16_t)(b0 | (b1 << 8));
  if (lane == 0) xs[r * 16 + kb] = s;
}

// ============ kernel 2: routing -> per-expert slot lists (slot = t*2+k) ============
__global__ void route_kernel(const void* __restrict__ idxraw,
                             int* __restrict__ list, int* __restrict__ cnt) {
  const long long* p = (const long long*)idxraw;
  unsigned hi = 0;
#pragma unroll
  for (int j = 0; j < 16; ++j) hi |= (unsigned)((unsigned long long)p[j] >> 32);
  const int i = blockIdx.x * 256 + threadIdx.x;
  int e;
  if (hi == 0) {
    e = (int)p[i];                       // int64 storage
  } else {
    long long v = p[i >> 1];             // int32 storage
    e = (int)((i & 1) ? (v >> 32) : (v & 0xffffffffLL));
  }
  e &= 7;
  const int pos = atomicAdd(&cnt[e], 1);
  list[e * MAXM + pos] = i;
}

// ============ kernel 3: gate_up GEMM + silu*up + h-quant ============
// 64x(128g+128u) tile, 256 thr (4 waves, 2M x 2N), BK=128. Grid (11,64,8).
// B double-buffered via gll16 (counted vmcnt); A reg-staged into single LDS buf.
// LDS ~78.6KB -> 2 blocks/CU.
__global__ __launch_bounds__(256) void gemm1_kernel(
    const uint8_t* __restrict__ xq, const float* __restrict__ xs,
    const uint8_t* __restrict__ w, const float* __restrict__ wscl,
    const int* __restrict__ list, const int* __restrict__ cnt,
    uint8_t* __restrict__ hq, float* __restrict__ hs) {
  const int e = blockIdx.z, mt = blockIdx.y, nb = blockIdx.x;
  const int M = cnt[e];
  if (mt * 64 >= M) return;
  __shared__ __align__(16) uint8_t As[8192];
  __shared__ __align__(16) uint8_t Bg[2 * 16384];
  __shared__ __align__(16) uint8_t Bu[2 * 16384];
  __shared__ int slots[64];
  __shared__ __align__(16) float sxsAll[16][64];
  __shared__ __align__(16) float amx[128];
  const int tid = threadIdx.x, lane = tid & 63, wid = tid >> 6;
  const int wr = wid >> 1, wc = wid & 1;
  if (tid < 64) {
    int m = mt * 64 + tid;
    slots[tid] = list[e * MAXM + (m < M ? m : 0)];
  }
  __syncthreads();
  // preload all activation scales transposed: sxsAll[kb][row]
  {
    const int r = tid >> 2, q = tid & 3;
    const int tok = slots[r] >> 1;
    f32x4 v = *(const f32x4*)(xs + (size_t)tok * 16 + q * 4);
    sxsAll[q * 4 + 0][r] = v[0];
    sxsAll[q * 4 + 1][r] = v[1];
    sxsAll[q * 4 + 2][r] = v[2];
    sxsAll[q * 4 + 3][r] = v[3];
  }
  const int s = tid >> 3;                           // 0..31
  const int cj0 = ((tid & 7) ^ (s & 7)) << 4;       // pre-swizzled source chunk
  const long tokA0 = slots[s] >> 1;
  const long tokA1 = slots[s + 32] >> 1;
  const uint8_t* pA0 = xq + tokA0 * HDIM + cj0;
  const uint8_t* pA1 = xq + tokA1 * HDIM + cj0;
  const size_t wb = (size_t)e * (2 * IDIM) * HDIM;
  const uint8_t* pG = w + wb + (size_t)(nb * 128 + s) * HDIM + cj0;
  const uint8_t* pU = w + wb + (size_t)(IDIM + nb * 128 + s) * HDIM + cj0;
  const float* wsg = wscl + (size_t)e * 352 + nb * 16;   // (E,22,16)
  const float* wsu = wsg + 176;
  f32x4 accg[2][4] = {};
  f32x4 accu[2][4] = {};
  const int kbyte = (lane >> 4) << 3;
#define STAGEB(d, kk) { const int ko_ = (kk) << 7; \
    _Pragma("unroll") \
    for (int k = 0; k < 4; ++k) { \
      gll16(pG + (size_t)(k * 32) * HDIM + ko_, Bg + (d) * 16384 + k * 4096 + tid * 16); \
      gll16(pU + (size_t)(k * 32) * HDIM + ko_, Bu + (d) * 16384 + k * 4096 + tid * 16); \
    } }
  // prologue: A(0) in regs, B(0) -> buf0
  f32x4 rA0 = *(const f32x4*)(pA0);
  f32x4 rA1 = *(const f32x4*)(pA1);
  STAGEB(0, 0)
  __syncthreads();   // drains vmcnt+lgkmcnt: B(0), sxsAll ready; rA in regs
  int cur = 0;
  for (int kb = 0; kb < NKB1; ++kb) {
    // write A(kb) to LDS (safe: As(kb-1) reads finished before prev B2 barrier)
    *(f32x4*)(As + tid * 16) = rA0;
    *(f32x4*)(As + 4096 + tid * 16) = rA1;
    if (kb + 1 < NKB1) {   // issue next tile: B->LDS async, A->regs
      STAGEB(cur ^ 1, kb + 1)
      const int ko = (kb + 1) << 7;
      rA0 = *(const f32x4*)(pA0 + ko);
      rA1 = *(const f32x4*)(pA1 + ko);
    }
    asm volatile("s_waitcnt lgkmcnt(0)" ::: "memory");   // ds_writes of A done
    __builtin_amdgcn_s_barrier();                        // B1: As(kb) visible
    const float swg = wsg[kb];
    const float swu = wsu[kb];
    const uint8_t* Bgb = Bg + cur * 16384;
    const uint8_t* Bub = Bu + cur * 16384;
    long af[2][4], bgf[4][4], buf_[4][4];
#pragma unroll
    for (int mi = 0; mi < 2; ++mi) {
      const int r = wr * 32 + mi * 16 + (lane & 15);
      const int xr = (r & 7) << 4;
      const uint8_t* bp = As + r * 128;
#pragma unroll
      for (int kc = 0; kc < 4; ++kc)
        af[mi][kc] = *(const long*)(bp + (((kc << 5) + kbyte) ^ xr));
    }
#pragma unroll
    for (int ni = 0; ni < 4; ++ni) {
      const int r = wc * 64 + ni * 16 + (lane & 15);
      const int xr = (r & 7) << 4;
      const uint8_t* bpg = Bgb + r * 128;
      const uint8_t* bpu = Bub + r * 128;
#pragma unroll
      for (int kc = 0; kc < 4; ++kc) {
        bgf[ni][kc] = *(const long*)(bpg + (((kc << 5) + kbyte) ^ xr));
        buf_[ni][kc] = *(const long*)(bpu + (((kc << 5) + kbyte) ^ xr));
      }
    }
    f32x4 sxg[2], sxu[2];
#pragma unroll
    for (int mi = 0; mi < 2; ++mi) {
      f32x4 sx = *(const f32x4*)(&sxsAll[kb][wr * 32 + mi * 16 + ((lane >> 4) << 2)]);
      sxg[mi] = sx * swg;
      sxu[mi] = sx * swu;
    }
    asm volatile("s_waitcnt lgkmcnt(0)" ::: "memory");
    __builtin_amdgcn_sched_barrier(0);
#pragma unroll
    for (int mi = 0; mi < 2; ++mi)
#pragma unroll
      for (int ni = 0; ni < 4; ++ni) {
        f32x4 pg = {0.f, 0.f, 0.f, 0.f};
        f32x4 pu = {0.f, 0.f, 0.f, 0.f};
#pragma unroll
        for (int kc = 0; kc < 4; ++kc) {
          pg = mfma_fp8(af[mi][kc], bgf[ni][kc], pg);
          pu = mfma_fp8(af[mi][kc], buf_[ni][kc], pu);
        }
#pragma unroll
        for (int j = 0; j < 4; ++j) {
          accg[mi][ni][j] += pg[j] * sxg[mi][j];
          accu[mi][ni][j] += pu[j] * sxu[mi][j];
        }
      }
    asm volatile("s_waitcnt vmcnt(0)" ::: "memory");   // B(kb+1) in LDS, A(kb+1) in regs
    __builtin_amdgcn_s_barrier();                      // B2
    cur ^= 1;
  }
#undef STAGEB
  // h = silu(g)*u; rowwise amax over 128 h-cols (one quant block)
  f32x4 hv[2][4];
  f32x4 rmax[2];
#pragma unroll
  for (int mi = 0; mi < 2; ++mi) {
#pragma unroll
    for (int ni = 0; ni < 4; ++ni)
#pragma unroll
      for (int j = 0; j < 4; ++j) {
        float g = accg[mi][ni][j];
        float u = accu[mi][ni][j];
        float h = (g / (1.f + expf(-g))) * u;
        hv[mi][ni][j] = h;
        float ah = fabsf(h);
        rmax[mi][j] = (ni == 0) ? ah : fmaxf(rmax[mi][j], ah);
      }
#pragma unroll
    for (int d = 1; d < 16; d <<= 1)
#pragma unroll
      for (int j = 0; j < 4; ++j)
        rmax[mi][j] = fmaxf(rmax[mi][j], __shfl_xor(rmax[mi][j], d));
  }
  __syncthreads();
  if ((lane & 15) == 0) {
#pragma unroll
    for (int mi = 0; mi < 2; ++mi)
#pragma unroll
      for (int j = 0; j < 4; ++j) {
        int row = wr * 32 + mi * 16 + ((lane >> 4) << 2) + j;
        amx[row * 2 + wc] = rmax[mi][j];
      }
  }
  __syncthreads();
  const int Mrem = M - mt * 64;
#pragma unroll
  for (int mi = 0; mi < 2; ++mi)
#pragma unroll
    for (int j = 0; j < 4; ++j) {
      const int row = wr * 32 + mi * 16 + ((lane >> 4) << 2) + j;
      float am = fmaxf(amx[row * 2], amx[row * 2 + 1]);
      float sq = fmaxf(am, 1e-12f) / 448.f;
      if (row < Mrem) {
        const int slot = slots[row];
        uint8_t* hp = hq + (size_t)slot * IDIM + nb * 128 + wc * 64 + (lane & 15);
#pragma unroll
        for (int ni = 0; ni < 4; ++ni)
          hp[ni * 16] = (uint8_t)f8_1(hv[mi][ni][j] / sq);
        if (wc == 0 && (lane & 15) == 0) hs[slot * 16 + nb] = sq;  // stride 16
      }
    }
}

// ============ kernel 4: down GEMM -> per-slot tmp (plain stores) ============
// 128x128 tile, 256 thr (4 waves, 2M x 2N), BK=128, full dbuf (R7 pattern).
// Grid (16, 32, 8). LDS ~74.8KB -> 2 blocks/CU.
__global__ __launch_bounds__(256) void gemm2_kernel(
    const uint8_t* __restrict__ hq, const float* __restrict__ hs,
    const uint8_t* __restrict__ w, const float* __restrict__ wscl,
    const int* __restrict__ list, const int* __restrict__ cnt,
    const float* __restrict__ tkw, float* __restrict__ tmp) {
  const int e = blockIdx.z, mt = blockIdx.y, nt = blockIdx.x;
  const int M = cnt[e];
  if (mt * 128 >= M) return;
  __shared__ __align__(16) uint8_t As[2 * 16384];
  __shared__ __align__(16) uint8_t Bs[2 * 16384];
  __shared__ int slots[128];
  __shared__ float rwl[128];
  __shared__ __align__(16) float sxsAll[16][128];
  const int tid = threadIdx.x, lane = tid & 63, wid = tid >> 6;
  const int wr = wid >> 1, wc = wid & 1;
  if (tid < 128) {
    int m = mt * 128 + tid;
    int slot = list[e * MAXM + (m < M ? m : 0)];
    slots[tid] = slot;
    rwl[tid] = (m < M) ? tkw[slot] : 0.f;
  }
  __syncthreads();
  {  // preload h scales transposed: 2 threads per row, 2 quads each
    const int r = tid >> 1, q2 = (tid & 1) * 2;
    const float* ps = hs + (size_t)slots[r] * 16;
#pragma unroll
    for (int qq = 0; qq < 2; ++qq) {
      f32x4 v = *(const f32x4*)(ps + (q2 + qq) * 4);
      sxsAll[(q2 + qq) * 4 + 0][r] = v[0];
      sxsAll[(q2 + qq) * 4 + 1][r] = v[1];
      sxsAll[(q2 + qq) * 4 + 2][r] = v[2];
      sxsAll[(q2 + qq) * 4 + 3][r] = v[3];
    }
  }
  const int s = tid >> 3;
  const int cj0 = ((tid & 7) ^ (s & 7)) << 4;
  const long sA0 = slots[s];
  const long sA1 = slots[s + 32];
  const long sA2 = slots[s + 64];
  const long sA3 = slots[s + 96];
  const uint8_t* pA0 = hq + sA0 * IDIM + cj0;
  const uint8_t* pA1 = hq + sA1 * IDIM + cj0;
  const uint8_t* pA2 = hq + sA2 * IDIM + cj0;
  const uint8_t* pA3 = hq + sA3 * IDIM + cj0;
  const uint8_t* pB = w + (size_t)e * HDIM * IDIM + (size_t)(nt * 128 + s) * IDIM + cj0;
  const float* wsd = wscl + (size_t)e * 176 + nt * 11;  // (E,16,11)
  f32x4 acc[4][4] = {};
  const int kbyte = (lane >> 4) << 3;
#define STAGE2(d, kk) { const int ko_ = (kk) << 7; \
    gll16(pA0 + ko_, As + (d) * 16384 + tid * 16); \
    gll16(pA1 + ko_, As + (d) * 16384 + 4096 + tid * 16); \
    gll16(pA2 + ko_, As + (d) * 16384 + 8192 + tid * 16); \
    gll16(pA3 + ko_, As + (d) * 16384 + 12288 + tid * 16); \
    _Pragma("unroll") \
    for (int k = 0; k < 4; ++k) \
      gll16(pB + (size_t)(k * 32) * IDIM + ko_, Bs + (d) * 16384 + k * 4096 + tid * 16); }
  STAGE2(0, 0)
  __syncthreads();
  int cur = 0;
  for (int kb = 0; kb < NKB2; ++kb) {
    if (kb + 1 < NKB2) STAGE2(cur ^ 1, kb + 1)
    const float swd = wsd[kb];
    const uint8_t* Ab = As + cur * 16384;
    const uint8_t* Bb = Bs + cur * 16384;
    long af[4][4], bf[4][4];
#pragma unroll
    for (int mi = 0; mi < 4; ++mi) {
      const int r = wr * 64 + mi * 16 + (lane & 15);
      const int xr = (r & 7) << 4;
      const uint8_t* bp = Ab + r * 128;
#pragma unroll
      for (int kc = 0; kc < 4; ++kc)
        af[mi][kc] = *(const long*)(bp + (((kc << 5) + kbyte) ^ xr));
    }
#pragma unroll
    for (int ni = 0; ni < 4; ++ni) {
      const int r = wc * 64 + ni * 16 + (lane & 15);
      const int xr = (r & 7) << 4;
      const uint8_t* bp = Bb + r * 128;
#pragma unroll
      for (int kc = 0; kc < 4; ++kc)
        bf[ni][kc] = *(const long*)(bp + (((kc << 5) + kbyte) ^ xr));
    }
    f32x4 sxd[4];
#pragma unroll
    for (int mi = 0; mi < 4; ++mi) {
      f32x4 sx = *(const f32x4*)(&sxsAll[kb][wr * 64 + mi * 16 + ((lane >> 4) << 2)]);
      sxd[mi] = sx * swd;
    }
    asm volatile("s_waitcnt lgkmcnt(0)" ::: "memory");
    __builtin_amdgcn_sched_barrier(0);
#pragma unroll
    for (int mi = 0; mi < 4; ++mi)
#pragma unroll
      for (int ni = 0; ni < 4; ++ni) {
        f32x4 p = {0.f, 0.f, 0.f, 0.f};
#pragma unroll
        for (int kc = 0; kc < 4; ++kc) p = mfma_fp8(af[mi][kc], bf[ni][kc], p);
#pragma unroll
        for (int j = 0; j < 4; ++j) acc[mi][ni][j] += p[j] * sxd[mi][j];
      }
    asm volatile("s_waitcnt vmcnt(0)" ::: "memory");
    __builtin_amdgcn_s_barrier();
    cur ^= 1;
  }
#undef STAGE2
  const int Mrem = M - mt * 128;
#pragma unroll
  for (int mi = 0; mi < 4; ++mi)
#pragma unroll
    for (int j = 0; j < 4; ++j) {
      const int row = wr * 64 + mi * 16 + ((lane >> 4) << 2) + j;
      if (row < Mrem) {
        const int slot = slots[row];
        const float rw = rwl[row];
        float* op = tmp + (size_t)slot * HDIM + nt * 128 + wc * 64 + (lane & 15);
#pragma unroll
        for (int ni = 0; ni < 4; ++ni) op[ni * 16] = rw * acc[mi][ni][j];
      }
    }
}

// ============ kernel 5: out[t] = tmp[2t] + tmp[2t+1] ============
__global__ void reduce_kernel(const float* __restrict__ tmp, float* __restrict__ out) {
  const int i = blockIdx.x * 256 + threadIdx.x;
  const int t = i >> 9, c4 = i & 511;
  const f32x4 a = ((const f32x4*)tmp)[(size_t)(2 * t) * 512 + c4];
  const f32x4 c = ((const f32x4*)tmp)[(size_t)(2 * t) * 512 + 512 + c4];
  ((f32x4*)out)[i] = a + c;
}

extern "C" void kernel_launch(void* const* d_in, const int* in_sizes, int n_in,
                              void* d_out, int out_size, void* d_ws, size_t ws_size,
                              hipStream_t stream) {
  const float* hidden = (const float*)d_in[0];
  const void* topk_idx = d_in[1];
  const float* topk_w = (const float*)d_in[2];
  const void* gup_raw = d_in[3];   // fp8 values held as f32 or bf16 (sniffed)
  const float* gup_s = (const float*)d_in[4];
  const void* dwn_raw = d_in[5];
  const float* dwn_s = (const float*)d_in[6];
  float* out = (float*)d_out;
  uint8_t* ws = (uint8_t*)d_ws;
  // workspace layout (~79.7 MB); tmp (32MB) aliases gq (dead after gemm1)
  uint8_t* xq = ws;                           //  4,194,304
  float* xs = (float*)(ws + 4194304);         //    131,072
  uint8_t* hq = ws + 4325376;                 //  5,767,168
  float* hs = (float*)(ws + 10092544);        //    262,144 (4096 x 16 f32, padded)
  int* list = (int*)(ws + 10354688);          //    131,072
  int* cnt = (int*)(ws + 10485760);           //         64
  int* modes = (int*)(ws + 10485824);         //         64
  uint8_t* gq = ws + 10485888;                // 46,137,344 (gate_up fp8)
  float* tmp = (float*)gq;                    // 33,554,432 (aliases gq; gemm2/reduce only)
  uint8_t* dq = ws + 56623232;                // 23,068,672 (down fp8)
  (void)in_sizes; (void)n_in; (void)ws_size; (void)out_size;

  sniff_kernel<<<1, 64, 0, stream>>>((const uint16_t*)gup_raw, (const uint16_t*)dwn_raw, modes, cnt);
  repack_kernel<<<(5767168 + 255) / 256, 256, 0, stream>>>(gup_raw, gq, 5767168, modes, 0);
  repack_kernel<<<(2883584 + 255) / 256, 256, 0, stream>>>(dwn_raw, dq, 2883584, modes, 1);
  quantx_kernel<<<8192, 256, 0, stream>>>(hidden, xq, xs);
  route_kernel<<<16, 256, 0, stream>>>(topk_idx, list, cnt);
  gemm1_kernel<<<dim3(11, 64, 8), 256, 0, stream>>>(xq, xs, gq, gup_s, list, cnt, hq, hs);
  gemm2_kernel<<<dim3(16, 32, 8), 256, 0, stream>>>(hq, hs, dq, dwn_s, list, cnt, topk_w, tmp);
  reduce_kernel<<<4096, 256, 0, stream>>>(tmp, out);
}